// Round 4
// baseline (466.141 us; speedup 1.0000x reference)
//
#include <hip/hip_runtime.h>
#include <hip/hip_cooperative_groups.h>

namespace cg = cooperative_groups;

#define NNODES 4096
#define HID 256
#define NG 16
#define NH 8
#define HD 32
#define LN_EPS 1e-5f
// (1/sqrt(32)) * log2(e): softmax in exp2 domain (exact wrt softmax)
#define QSCALE (0.17677669529663687f * 1.4426950408889634f)
#define CAPT 384          // max padded segment length (>> 6 sigma above mean 256)
#define KLS 40            // K row stride (elems): 20-dword lane stride -> 2-way banks only
#define VTS (CAPT + 2)    // V^T row stride (elements): odd-dword to spread banks

typedef unsigned short u16;
typedef unsigned int u32;
typedef __bf16 bf16x8 __attribute__((ext_vector_type(8)));
typedef float f32x4 __attribute__((ext_vector_type(4)));

__device__ __forceinline__ u16 f2bf(float f){
  union { float f; u32 i; } c; c.f = f;
  u32 x = c.i;
  return (u16)((x + 0x7fffu + ((x >> 16) & 1u)) >> 16);  // RNE
}

struct Params {
  const float* x; const int* batch;
  const float* Wq; const float* bq;
  const float* Wk; const float* bk;
  const float* Wv; const float* bv;
  const float* Wo; const float* bo;
  const float* gamma; const float* beta;
  int* seg; u16* Wt; u16* h; u16* qb; u16* kb; u16* vb; u16* ao;
  float* out;
};

// ---------------------------------------------------------------------------
// Phase A: LN (2 rows per wave) + weight transpose (blocks 0..255) + seg (511)
__device__ __forceinline__ void phaseA(const Params& p){
  __shared__ u16 tile[32][33];
  __shared__ int bad;
  int bid = blockIdx.x, tid = threadIdx.x;
  int wave = tid >> 6, lane = tid & 63;
  int wgid = bid * 4 + wave;                 // 0..2047
  #pragma unroll
  for (int ps = 0; ps < 2; ps++){
    int row = wgid + ps * 2048;
    float4 xv = ((const float4*)p.x)[row * 64 + lane];
    float a0 = xv.x, a1 = xv.y, a2 = xv.z, a3 = xv.w;
    float s = a0 + a1 + a2 + a3;
    #pragma unroll
    for (int m = 1; m < 64; m <<= 1) s += __shfl_xor(s, m);
    float mu = s * (1.0f / HID);
    float d0 = a0 - mu, d1 = a1 - mu, d2 = a2 - mu, d3 = a3 - mu;
    float vv = d0*d0 + d1*d1 + d2*d2 + d3*d3;
    #pragma unroll
    for (int m = 1; m < 64; m <<= 1) vv += __shfl_xor(vv, m);
    float rs = rsqrtf(vv * (1.0f / HID) + LN_EPS);
    float4 gv = ((const float4*)p.gamma)[lane];
    float4 bv = ((const float4*)p.beta)[lane];
    ushort4 o;
    o.x = f2bf(d0 * rs * gv.x + bv.x);
    o.y = f2bf(d1 * rs * gv.y + bv.y);
    o.z = f2bf(d2 * rs * gv.z + bv.z);
    o.w = f2bf(d3 * rs * gv.w + bv.w);
    *(ushort4*)(p.h + (size_t)row * HID + lane * 4) = o;
  }
  if (bid < 256){
    // ---- Transpose 4x 256x256 f32 weights -> bf16 Wt[n][k] = W[k][n] ----
    int w = bid >> 6;              // 64 tiles (8x8) per matrix
    int t = bid & 63;
    int bx = (t & 7) * 32, by = (t >> 3) * 32;
    const float* src = (w == 0) ? p.Wq : (w == 1) ? p.Wk : (w == 2) ? p.Wv : p.Wo;
    u16* dst = p.Wt + (size_t)w * HID * HID;
    int tx = tid & 31, ty = tid >> 5;   // 32 x 8
    #pragma unroll
    for (int r = 0; r < 32; r += 8)
      tile[ty + r][tx] = f2bf(src[(size_t)(by + ty + r) * HID + bx + tx]);
    __syncthreads();
    #pragma unroll
    for (int r = 0; r < 32; r += 8)
      dst[(size_t)(bx + ty + r) * HID + by + tx] = tile[tx][ty + r];
  }
  if (bid == 511){
    // ---- Segment boundaries; int64-vs-int32 auto-detect ----
    const int* bw = p.batch;
    if (tid == 0) bad = 0;
    __syncthreads();
    int local_bad = 0;
    for (int i = tid; i < NNODES; i += 256){
      int v = bw[i];
      if (v < 0 || v > 15) local_bad = 1;
      if (i + 1 < NNODES && bw[i + 1] < v) local_bad = 1;
    }
    if (local_bad) atomicOr(&bad, 1);
    __syncthreads();
    int stride = bad ? 2 : 1;  // bad => actually int64
    int g = tid;
    if (g <= NG){
      int lo = 0, hi = NNODES;
      while (lo < hi){
        int mid = (lo + hi) >> 1;
        if (bw[mid * stride] < g) lo = mid + 1; else hi = mid;
      }
      p.seg[g] = lo;
    }
  }
}

// ---------------------------------------------------------------------------
// Phase B: fused QKV GEMM. 2048 waves, each owns one 32m x 16n tile position
// and computes Q,K,V for it (A-frags loaded once: 5 loads / 6 MFMAs per k0).
// mfma_f32_16x16x32_bf16 layouts (m89-verified): A lane = A[m=lane&15][k=(lane>>4)*8+j];
// B lane = B[k][n=lane&15]; C/D: col=lane&15, row=(lane>>4)*4+reg.
__device__ __forceinline__ void phaseB(const Params& p){
  int wgid = blockIdx.x * 4 + (threadIdx.x >> 6);   // 0..2047 = tile id
  int lane = threadIdx.x & 63;
  int lr = lane & 15, lq = lane >> 4;
  int m0 = (wgid >> 4) * 32, n0 = (wgid & 15) * 16;
  const u16* a0p = p.h + (size_t)(m0 + lr) * HID + lq * 8;
  const u16* a1p = a0p + (size_t)16 * HID;
  const u16* bqp = p.Wt + (size_t)(n0 + lr) * HID + lq * 8;
  const u16* bkp = bqp + (size_t)HID * HID;
  const u16* bvp = bqp + (size_t)2 * HID * HID;
  f32x4 aq[2] = {}, ak[2] = {}, av[2] = {};
  #pragma unroll
  for (int k0 = 0; k0 < HID; k0 += 32){
    bf16x8 a0 = *(const bf16x8*)(a0p + k0);
    bf16x8 a1 = *(const bf16x8*)(a1p + k0);
    bf16x8 wq = *(const bf16x8*)(bqp + k0);
    bf16x8 wk = *(const bf16x8*)(bkp + k0);
    bf16x8 wv = *(const bf16x8*)(bvp + k0);
    aq[0] = __builtin_amdgcn_mfma_f32_16x16x32_bf16(a0, wq, aq[0], 0, 0, 0);
    aq[1] = __builtin_amdgcn_mfma_f32_16x16x32_bf16(a1, wq, aq[1], 0, 0, 0);
    ak[0] = __builtin_amdgcn_mfma_f32_16x16x32_bf16(a0, wk, ak[0], 0, 0, 0);
    ak[1] = __builtin_amdgcn_mfma_f32_16x16x32_bf16(a1, wk, ak[1], 0, 0, 0);
    av[0] = __builtin_amdgcn_mfma_f32_16x16x32_bf16(a0, wv, av[0], 0, 0, 0);
    av[1] = __builtin_amdgcn_mfma_f32_16x16x32_bf16(a1, wv, av[1], 0, 0, 0);
  }
  int col = n0 + lr;
  float cq = p.bq[col], ck = p.bk[col], cv = p.bv[col];
  #pragma unroll
  for (int t = 0; t < 2; t++){
    #pragma unroll
    for (int r = 0; r < 4; r++){
      size_t row = (size_t)(m0 + 16 * t + lq * 4 + r) * HID + col;
      p.qb[row] = f2bf(aq[t][r] + cq);
      p.kb[row] = f2bf(ak[t][r] + ck);
      p.vb[row] = f2bf(av[t][r] + cv);
    }
  }
}

// ---------------------------------------------------------------------------
// Phase C: MFMA flash attention (r2-proven numerics). One block per
// (quarter, graph, head); stages K -> kl[j][d] (stride 40), V^T -> vt[d][j];
// each wave owns one q-tile (t = it*16 + quarter*4 + wave), full j-range,
// online softmax in exp2 domain; Q-frag straight from global qb.
__device__ __forceinline__ void phaseC(const Params& p){
  __shared__ u16 kl[CAPT * KLS];        // K  [j][k], padded stride
  __shared__ u16 vt[HD * VTS];          // V^T [d][j]
  int job = blockIdx.x;
  int quarter = job & 3, gh = job >> 2;
  int g = gh >> 3, hd = gh & 7;
  int start = p.seg[g], end = p.seg[g + 1];
  int len = end - start;
  if (len <= 0) return;               // block-uniform; no grid-wide ops inside
  if (len > CAPT) len = CAPT;         // unreachable for this input distribution
  int ntj = (len + 15) >> 4;          // 16-row j-tiles (also q-tiles)
  int nj16 = ntj << 4;
  int tid = threadIdx.x;
  // stage K (zero-padded to nj16 rows), 16B per lane
  for (int idx = tid; idx < nj16 * 4; idx += 256){
    int row = idx >> 2, part = idx & 3;
    uint4 val = make_uint4(0, 0, 0, 0);
    if (row < len)
      val = *(const uint4*)&p.kb[(size_t)(start + row) * HID + hd * HD + part * 8];
    *(uint4*)&kl[row * KLS + part * 8] = val;
  }
  // stage V transposed (vt[d][j]), 16B global loads
  for (int idx = tid; idx < nj16 * 4; idx += 256){
    int row = idx >> 2, part = idx & 3;
    uint4 w = make_uint4(0, 0, 0, 0);
    if (row < len)
      w = *(const uint4*)&p.vb[(size_t)(start + row) * HID + hd * HD + part * 8];
    int d0 = part * 8;
    vt[(d0 + 0) * VTS + row] = (u16)(w.x & 0xffffu);
    vt[(d0 + 1) * VTS + row] = (u16)(w.x >> 16);
    vt[(d0 + 2) * VTS + row] = (u16)(w.y & 0xffffu);
    vt[(d0 + 3) * VTS + row] = (u16)(w.y >> 16);
    vt[(d0 + 4) * VTS + row] = (u16)(w.z & 0xffffu);
    vt[(d0 + 5) * VTS + row] = (u16)(w.z >> 16);
    vt[(d0 + 6) * VTS + row] = (u16)(w.w & 0xffffu);
    vt[(d0 + 7) * VTS + row] = (u16)(w.w >> 16);
  }
  __syncthreads();
  int wave = tid >> 6, lane = tid & 63;
  int lq = lane >> 4, lr = lane & 15;
  int nouter = (ntj + 15) >> 4;       // <= 2
  for (int it = 0; it < nouter; it++){
    int tq = it * 16 + quarter * 4 + wave;
    if (tq >= ntj) continue;
    int q0 = tq << 4;
    // Q B-frag, register-resident. Rows past len read adjacent ws memory
    // (finite bf16), masked at the store.
    bf16x8 qf = *(const bf16x8*)&p.qb[(size_t)(start + q0 + lr) * HID + hd * HD + lq * 8];
    float m = -3.0e38f, l = 0.f;
    f32x4 o0 = {0.f,0.f,0.f,0.f}, o1 = {0.f,0.f,0.f,0.f};
    for (int jt = 0; jt < ntj; jt++){
      int j0 = jt << 4;
      bf16x8 kf = *(const bf16x8*)&kl[(j0 + lr) * KLS + lq * 8];
      f32x4 st = __builtin_amdgcn_mfma_f32_16x16x32_bf16(kf, qf,
                   (f32x4){0.f,0.f,0.f,0.f}, 0, 0, 0);
      int jb = j0 + lq * 4;
      float s0 = (jb + 0 < len) ? st[0] * QSCALE : -3.0e38f;
      float s1 = (jb + 1 < len) ? st[1] * QSCALE : -3.0e38f;
      float s2 = (jb + 2 < len) ? st[2] * QSCALE : -3.0e38f;
      float s3 = (jb + 3 < len) ? st[3] * QSCALE : -3.0e38f;
      float tm = fmaxf(fmaxf(s0, s1), fmaxf(s2, s3));
      tm = fmaxf(tm, __shfl_xor(tm, 16));
      tm = fmaxf(tm, __shfl_xor(tm, 32));
      float mn = fmaxf(m, tm);
      float alpha = exp2f(m - mn);       // first tile: exp2(-huge) = 0
      float p0 = exp2f(s0 - mn), p1 = exp2f(s1 - mn);
      float p2 = exp2f(s2 - mn), p3 = exp2f(s3 - mn);
      float ps = (p0 + p1) + (p2 + p3);
      ps += __shfl_xor(ps, 16);
      ps += __shfl_xor(ps, 32);
      l = l * alpha + ps;
      m = mn;
      union { bf16x8 v8; u32 w[4]; } pf, vf0, vf1;
      pf.w[0] = (u32)f2bf(p0) | ((u32)f2bf(p1) << 16);
      pf.w[1] = (u32)f2bf(p2) | ((u32)f2bf(p3) << 16);
      pf.w[2] = 0; pf.w[3] = 0;
      const u16* vp0 = &vt[lr * VTS + j0 + lq * 4];
      const u16* vp1 = &vt[(16 + lr) * VTS + j0 + lq * 4];
      vf0.w[0] = *(const u32*)vp0; vf0.w[1] = *(const u32*)(vp0 + 2);
      vf0.w[2] = 0; vf0.w[3] = 0;
      vf1.w[0] = *(const u32*)vp1; vf1.w[1] = *(const u32*)(vp1 + 2);
      vf1.w[2] = 0; vf1.w[3] = 0;
      o0 = o0 * alpha;
      o1 = o1 * alpha;
      o0 = __builtin_amdgcn_mfma_f32_16x16x32_bf16(vf0.v8, pf.v8, o0, 0, 0, 0);
      o1 = __builtin_amdgcn_mfma_f32_16x16x32_bf16(vf1.v8, pf.v8, o1, 0, 0, 0);
    }
    if (q0 + lr < len){
      float rl = 1.0f / l;               // l >= 1 (own max contributes 1)
      u16* orow = p.ao + (size_t)(start + q0 + lr) * HID + hd * HD;
      int dbase = lq * 4;
      *(u32*)&orow[dbase]          = (u32)f2bf(o0[0]*rl) | ((u32)f2bf(o0[1]*rl) << 16);
      *(u32*)&orow[dbase + 2]      = (u32)f2bf(o0[2]*rl) | ((u32)f2bf(o0[3]*rl) << 16);
      *(u32*)&orow[16 + dbase]     = (u32)f2bf(o1[0]*rl) | ((u32)f2bf(o1[1]*rl) << 16);
      *(u32*)&orow[16 + dbase + 2] = (u32)f2bf(o1[2]*rl) | ((u32)f2bf(o1[3]*rl) << 16);
    }
  }
}

// ---------------------------------------------------------------------------
// Phase D: output projection + bias + residual. 2048 waves, one 32m x 16n
// tile each; C = ao * WtO^T + bo + x, stored f32.
__device__ __forceinline__ void phaseD(const Params& p){
  int wgid = blockIdx.x * 4 + (threadIdx.x >> 6);   // 0..2047 = tile id
  int lane = threadIdx.x & 63;
  int lr = lane & 15, lq = lane >> 4;
  int m0 = (wgid >> 4) * 32, n0 = (wgid & 15) * 16;
  const u16* a0p = p.ao + (size_t)(m0 + lr) * HID + lq * 8;
  const u16* a1p = a0p + (size_t)16 * HID;
  const u16* bp  = p.Wt + (size_t)3 * HID * HID + (size_t)(n0 + lr) * HID + lq * 8;
  f32x4 acc[2] = {};
  #pragma unroll
  for (int k0 = 0; k0 < HID; k0 += 32){
    bf16x8 b  = *(const bf16x8*)(bp + k0);
    bf16x8 a0 = *(const bf16x8*)(a0p + k0);
    bf16x8 a1 = *(const bf16x8*)(a1p + k0);
    acc[0] = __builtin_amdgcn_mfma_f32_16x16x32_bf16(a0, b, acc[0], 0, 0, 0);
    acc[1] = __builtin_amdgcn_mfma_f32_16x16x32_bf16(a1, b, acc[1], 0, 0, 0);
  }
  int col = n0 + lr;
  float bb = p.bo[col];
  #pragma unroll
  for (int t = 0; t < 2; t++){
    #pragma unroll
    for (int r = 0; r < 4; r++){
      size_t row = (size_t)(m0 + 16 * t + lq * 4 + r) * HID + col;
      p.out[row] = acc[t][r] + bb + p.x[row];
    }
  }
}

// ---------------------------------------------------------------------------
// Cooperative mega-kernel: 512 blocks x 256 threads, 57.5 KB LDS -> 2/CU.
// Three grid-wide syncs replace three kernel-launch boundaries.
__global__ __launch_bounds__(256, 2) void fused_kernel(Params p){
  phaseA(p);
  __threadfence();
  cg::this_grid().sync();
  phaseB(p);
  __threadfence();
  cg::this_grid().sync();
  phaseC(p);
  __threadfence();
  cg::this_grid().sync();
  phaseD(p);
}

// Fallback: identical phases as plain kernels (if cooperative launch refused).
__global__ __launch_bounds__(256, 2) void kA(Params p){ phaseA(p); }
__global__ __launch_bounds__(256, 2) void kB(Params p){ phaseB(p); }
__global__ __launch_bounds__(256, 2) void kC(Params p){ phaseC(p); }
__global__ __launch_bounds__(256, 2) void kD(Params p){ phaseD(p); }

// ---------------------------------------------------------------------------
// ws_size guard: paint an unmistakable sentinel if scratch is insufficient.
__global__ void sentinel_kernel(u32* __restrict__ out, int nwords){
  int i = blockIdx.x * 256 + threadIdx.x;
  if (i < nwords) out[i] = 0x46404640u;
}

// ---------------------------------------------------------------------------
extern "C" void kernel_launch(void* const* d_in, const int* in_sizes, int n_in,
                              void* d_out, int out_size, void* d_ws, size_t ws_size,
                              hipStream_t stream){
  const size_t WT_OFF = 1024;
  const size_t H_OFF  = WT_OFF + 4 * HID * HID * 2;         // 512 KB of Wt
  const size_t BUF    = (size_t)NNODES * HID * 2;           // 2 MB each (bf16)
  const size_t NEED   = H_OFF + 5 * BUF;                    // ~11 MB

  if (ws_size < NEED){
    int nwords = out_size / 2;
    sentinel_kernel<<<(nwords + 255) / 256, 256, 0, stream>>>((u32*)d_out, nwords);
    return;
  }

  char* w = (char*)d_ws;
  Params prm;
  prm.x     = (const float*)d_in[0];
  prm.batch = (const int*)d_in[1];
  prm.Wq = (const float*)d_in[2];  prm.bq = (const float*)d_in[3];
  prm.Wk = (const float*)d_in[4];  prm.bk = (const float*)d_in[5];
  prm.Wv = (const float*)d_in[6];  prm.bv = (const float*)d_in[7];
  prm.Wo = (const float*)d_in[8];  prm.bo = (const float*)d_in[9];
  prm.gamma = (const float*)d_in[10]; prm.beta = (const float*)d_in[11];
  prm.seg = (int*)(w + 128);
  prm.Wt  = (u16*)(w + WT_OFF);
  prm.h   = (u16*)(w + H_OFF);
  prm.qb  = prm.h  + (size_t)NNODES * HID;
  prm.kb  = prm.qb + (size_t)NNODES * HID;
  prm.vb  = prm.kb + (size_t)NNODES * HID;
  prm.ao  = prm.vb + (size_t)NNODES * HID;
  prm.out = (float*)d_out;

  void* args[] = { (void*)&prm };
  hipError_t e = hipLaunchCooperativeKernel((const void*)fused_kernel,
                                            dim3(512), dim3(256), args, 0, stream);
  if (e != hipSuccess){
    // Cooperative launch unavailable: same phases, plain launches.
    kA<<<512, 256, 0, stream>>>(prm);
    kB<<<512, 256, 0, stream>>>(prm);
    kC<<<512, 256, 0, stream>>>(prm);
    kD<<<512, 256, 0, stream>>>(prm);
  }
}

// Round 6
// 115.796 us; speedup vs baseline: 4.0255x; 4.0255x over previous
//
#include <hip/hip_runtime.h>

#define NNODES 4096
#define HID 256
#define NG 16
#define NH 8
#define HD 32
#define LN_EPS 1e-5f
// (1/sqrt(32)) * log2(e): softmax in exp2 domain (exact wrt softmax)
#define QSCALE (0.17677669529663687f * 1.4426950408889634f)
#define CAPT 384          // max padded segment length (>> 6 sigma above mean 256)
#define KLS 40            // K row stride (elems): 20-dword lane stride -> 2-way banks only
#define VTS (CAPT + 2)    // V^T row stride (elements): odd-dword to spread banks
#define HLS 264           // LDS h-tile row stride (elems): 33*16B rows, staggered banks

typedef unsigned short u16;
typedef unsigned int u32;
typedef __bf16 bf16x8 __attribute__((ext_vector_type(8)));
typedef float f32x4 __attribute__((ext_vector_type(4)));

__device__ __forceinline__ u16 f2bf(float f){
  union { float f; u32 i; } c; c.f = f;
  u32 x = c.i;
  return (u16)((x + 0x7fffu + ((x >> 16) & 1u)) >> 16);  // RNE
}

// ---------------------------------------------------------------------------
// lnqkv: fused LayerNorm + QKV GEMM. Grid (256, 3) x 256 thr, 3 blocks/CU.
// Block = 64m x 64n of one of {Q,K,V}. LN of the block's 64 rows is computed
// in-block into LDS (h-tile, bf16) -- row-local, so no inter-block dependency;
// 12x redundant across (4 n-quads x 3 matrices) but trivially cheap and all
// L2-hit. B-fragments are built from W (f32, [k][n]) directly with the same
// f2bf as the old Wt path -> bit-identical GEMM inputs, no transpose kernel.
// MFMA layouts (m89-verified): A lane = A[m=lane&15][k=(lane>>4)*8+j];
// B lane = B[k][n=lane&15]; C/D: col=lane&15, row=(lane>>4)*4+reg.
__global__ __launch_bounds__(256) void lnqkv_kernel(
    const float* __restrict__ x, const float* __restrict__ gamma,
    const float* __restrict__ beta,
    const float* __restrict__ Wq, const float* __restrict__ Wk,
    const float* __restrict__ Wv,
    const float* __restrict__ bq, const float* __restrict__ bk,
    const float* __restrict__ bv,
    u16* __restrict__ qb, u16* __restrict__ kb, u16* __restrict__ vb){
  __shared__ u16 hl[64][HLS];
  int bid = blockIdx.x;            // 0..255
  int which = blockIdx.y;          // 0 = Q, 1 = K, 2 = V
  int wave = threadIdx.x >> 6, lane = threadIdx.x & 63;
  int m0 = (bid >> 2) * 64;                  // 64-row tile
  int nb = (bid & 3) * 64 + wave * 16;       // wave's 16-col slice
  const float* W    = (which == 0) ? Wq : (which == 1) ? Wk : Wv;
  const float* bias = (which == 0) ? bq : (which == 1) ? bk : bv;
  u16* out          = (which == 0) ? qb : (which == 1) ? kb : vb;

  // ---- LN: wave handles rows wave*16..+15, 4 rows at a time.
  // lane = rsub*16 + c16: rsub = row-in-batch, c16 = 16-col group.
  int rsub = lane >> 4;
  int c16  = lane & 15;
  float4 g0 = *(const float4*)(gamma + c16 * 16 + 0);
  float4 g1 = *(const float4*)(gamma + c16 * 16 + 4);
  float4 g2 = *(const float4*)(gamma + c16 * 16 + 8);
  float4 g3 = *(const float4*)(gamma + c16 * 16 + 12);
  float4 t0 = *(const float4*)(beta + c16 * 16 + 0);
  float4 t1 = *(const float4*)(beta + c16 * 16 + 4);
  float4 t2 = *(const float4*)(beta + c16 * 16 + 8);
  float4 t3 = *(const float4*)(beta + c16 * 16 + 12);
  float ga[16] = {g0.x,g0.y,g0.z,g0.w, g1.x,g1.y,g1.z,g1.w,
                  g2.x,g2.y,g2.z,g2.w, g3.x,g3.y,g3.z,g3.w};
  float bt[16] = {t0.x,t0.y,t0.z,t0.w, t1.x,t1.y,t1.z,t1.w,
                  t2.x,t2.y,t2.z,t2.w, t3.x,t3.y,t3.z,t3.w};
  #pragma unroll
  for (int b = 0; b < 4; b++){
    int rloc = wave * 16 + b * 4 + rsub;
    const float* xr = x + (size_t)(m0 + rloc) * HID + c16 * 16;
    float4 v0 = *(const float4*)(xr + 0);
    float4 v1 = *(const float4*)(xr + 4);
    float4 v2 = *(const float4*)(xr + 8);
    float4 v3 = *(const float4*)(xr + 12);
    float e[16] = {v0.x,v0.y,v0.z,v0.w, v1.x,v1.y,v1.z,v1.w,
                   v2.x,v2.y,v2.z,v2.w, v3.x,v3.y,v3.z,v3.w};
    float s = 0.f;
    #pragma unroll
    for (int i = 0; i < 16; i++) s += e[i];
    s += __shfl_xor(s, 1); s += __shfl_xor(s, 2);
    s += __shfl_xor(s, 4); s += __shfl_xor(s, 8);
    float mu = s * (1.0f / HID);
    float vv = 0.f;
    #pragma unroll
    for (int i = 0; i < 16; i++){ e[i] -= mu; vv += e[i] * e[i]; }
    vv += __shfl_xor(vv, 1); vv += __shfl_xor(vv, 2);
    vv += __shfl_xor(vv, 4); vv += __shfl_xor(vv, 8);
    float rs = rsqrtf(vv * (1.0f / HID) + LN_EPS);
    u32 pk[8];
    #pragma unroll
    for (int i = 0; i < 8; i++){
      float o0 = e[2*i]     * rs * ga[2*i]     + bt[2*i];
      float o1 = e[2*i + 1] * rs * ga[2*i + 1] + bt[2*i + 1];
      pk[i] = (u32)f2bf(o0) | ((u32)f2bf(o1) << 16);
    }
    *(uint4*)&hl[rloc][c16 * 16]     = make_uint4(pk[0], pk[1], pk[2], pk[3]);
    *(uint4*)&hl[rloc][c16 * 16 + 8] = make_uint4(pk[4], pk[5], pk[6], pk[7]);
  }
  __syncthreads();

  // ---- GEMM: wave = 64m x 16n; A from LDS h-tile, B from f32 W (strided).
  int lr = lane & 15, lq = lane >> 4;
  f32x4 acc[4] = {};
  const float* wbase = W + nb + lr;
  #pragma unroll
  for (int k0 = 0; k0 < HID; k0 += 32){
    union { bf16x8 v; u16 e[8]; } bf;
    const float* wp = wbase + (size_t)(k0 + lq * 8) * HID;
    #pragma unroll
    for (int j = 0; j < 8; j++) bf.e[j] = f2bf(wp[(size_t)j * HID]);
    #pragma unroll
    for (int t = 0; t < 4; t++){
      bf16x8 a = *(const bf16x8*)&hl[t * 16 + lr][k0 + lq * 8];
      acc[t] = __builtin_amdgcn_mfma_f32_16x16x32_bf16(a, bf.v, acc[t], 0, 0, 0);
    }
  }
  int col = nb + lr;
  float bb = bias[col];
  #pragma unroll
  for (int t = 0; t < 4; t++){
    #pragma unroll
    for (int r = 0; r < 4; r++){
      int row = m0 + 16 * t + lq * 4 + r;
      out[(size_t)row * HID + col] = f2bf(acc[t][r] + bb);
    }
  }
}

// ---------------------------------------------------------------------------
// MFMA flash attention -- the r0-proven 512-thread wave-pair kernel, with seg
// replaced by an in-block 2-level 64-ary lower_bound over batch (bstride from
// host: 2 if int64, 1 if int32). Grid (4, 128): 2 blocks/CU x 8 waves.
// Wave-pairs (w, w+4) share a q-tile and split the j-range; exact LDS merge.
__global__ __launch_bounds__(512, 4) void attn_kernel(const u16* __restrict__ q,
    const u16* __restrict__ k, const u16* __restrict__ v,
    const int* __restrict__ batch, int bstride, u16* __restrict__ out){
  __shared__ u16 kl[CAPT * KLS];        // K  [j][d], padded stride
  __shared__ u16 vt[HD * VTS];          // V^T [d][j]
  __shared__ float mg[4][10][64];       // merge: [tile][o0x4,o1x4,m,l][lane]
  __shared__ int s_se[2];
  int gh = blockIdx.y;
  int g = gh >> 3, hd = gh & 7;
  int wave = threadIdx.x >> 6, lane = threadIdx.x & 63;
  // ---- lower_bound(batch, g) / (g+1): waves 0 and 1, two ballot rounds.
  if (wave < 2){
    int target = g + wave;
    int p = batch[(size_t)(lane * 64) * bstride];
    int c = __popcll(__ballot(p < target));
    int lo = 0;
    if (c > 0){
      int base = (c - 1) * 64 + 1;
      int idx = base + lane;
      int val = (idx < NNODES) ? batch[(size_t)idx * bstride] : 0x7fffffff;
      lo = base + __popcll(__ballot(val < target));
    }
    if (lane == 0) s_se[wave] = lo;
  }
  __syncthreads();
  int start = s_se[0], end = s_se[1];
  int len = end - start;
  if (len <= 0) return;               // block-uniform
  if (len > CAPT) len = CAPT;         // unreachable for this input distribution
  int ntj = (len + 15) >> 4;          // 16-row j-tiles (also q-tiles)
  int nj16 = ntj << 4;
  // stage K (zero-padded to nj16 rows), 16B per lane
  for (int idx = threadIdx.x; idx < nj16 * 4; idx += 512){
    int row = idx >> 2, part = idx & 3;
    uint4 val = make_uint4(0, 0, 0, 0);
    if (row < len)
      val = *(const uint4*)&k[(size_t)(start + row) * HID + hd * HD + part * 8];
    *(uint4*)&kl[row * KLS + part * 8] = val;
  }
  // stage V transposed (vt[d][j]), 16B global loads
  for (int idx = threadIdx.x; idx < nj16 * 4; idx += 512){
    int row = idx >> 2, part = idx & 3;
    uint4 w = make_uint4(0, 0, 0, 0);
    if (row < len)
      w = *(const uint4*)&v[(size_t)(start + row) * HID + hd * HD + part * 8];
    int d0 = part * 8;
    vt[(d0 + 0) * VTS + row] = (u16)(w.x & 0xffffu);
    vt[(d0 + 1) * VTS + row] = (u16)(w.x >> 16);
    vt[(d0 + 2) * VTS + row] = (u16)(w.y & 0xffffu);
    vt[(d0 + 3) * VTS + row] = (u16)(w.y >> 16);
    vt[(d0 + 4) * VTS + row] = (u16)(w.z & 0xffffu);
    vt[(d0 + 5) * VTS + row] = (u16)(w.z >> 16);
    vt[(d0 + 6) * VTS + row] = (u16)(w.w & 0xffffu);
    vt[(d0 + 7) * VTS + row] = (u16)(w.w >> 16);
  }
  __syncthreads();
  int lq = lane >> 4, lr = lane & 15;
  int tl = wave & 3;                  // tile slot within block
  int jh = wave >> 2;                 // j-half (0 or 1)
  int nouter = (ntj + 15) >> 4;       // usually 1-2
  for (int it = 0; it < nouter; it++){
    int tq = it * 16 + blockIdx.x * 4 + tl;
    bool active = tq < ntj;
    int q0 = tq << 4;
    float m = -3.0e38f, l = 0.f;
    f32x4 o0 = {0.f,0.f,0.f,0.f}, o1 = {0.f,0.f,0.f,0.f};
    if (active){
      // Q B-frag, register-resident. Rows past len read adjacent ws memory
      // (finite bf16), masked at the store.
      bf16x8 qf = *(const bf16x8*)&q[(size_t)(start + q0 + lr) * HID + hd * HD + lq * 8];
      int half = (ntj + 1) >> 1;
      int jt0 = jh ? half : 0;
      int jt1 = jh ? ntj : half;
      for (int jt = jt0; jt < jt1; jt++){
        int j0 = jt << 4;
        bf16x8 kf = *(const bf16x8*)&kl[(j0 + lr) * KLS + lq * 8];
        f32x4 st = __builtin_amdgcn_mfma_f32_16x16x32_bf16(kf, qf,
                     (f32x4){0.f,0.f,0.f,0.f}, 0, 0, 0);
        int jb = j0 + lq * 4;
        float s0 = (jb + 0 < len) ? st[0] * QSCALE : -3.0e38f;
        float s1 = (jb + 1 < len) ? st[1] * QSCALE : -3.0e38f;
        float s2 = (jb + 2 < len) ? st[2] * QSCALE : -3.0e38f;
        float s3 = (jb + 3 < len) ? st[3] * QSCALE : -3.0e38f;
        float tm = fmaxf(fmaxf(s0, s1), fmaxf(s2, s3));
        tm = fmaxf(tm, __shfl_xor(tm, 16));
        tm = fmaxf(tm, __shfl_xor(tm, 32));
        float mn = fmaxf(m, tm);
        float alpha = exp2f(m - mn);       // first tile: exp2(-huge) = 0
        float p0 = exp2f(s0 - mn), p1 = exp2f(s1 - mn);
        float p2 = exp2f(s2 - mn), p3 = exp2f(s3 - mn);
        float ps = (p0 + p1) + (p2 + p3);
        ps += __shfl_xor(ps, 16);
        ps += __shfl_xor(ps, 32);
        l = l * alpha + ps;
        m = mn;
        union { bf16x8 v8; u32 w[4]; } pf, vf0, vf1;
        pf.w[0] = (u32)f2bf(p0) | ((u32)f2bf(p1) << 16);
        pf.w[1] = (u32)f2bf(p2) | ((u32)f2bf(p3) << 16);
        pf.w[2] = 0; pf.w[3] = 0;
        const u16* vp0 = &vt[lr * VTS + j0 + lq * 4];
        const u16* vp1 = &vt[(16 + lr) * VTS + j0 + lq * 4];
        vf0.w[0] = *(const u32*)vp0; vf0.w[1] = *(const u32*)(vp0 + 2);
        vf0.w[2] = 0; vf0.w[3] = 0;
        vf1.w[0] = *(const u32*)vp1; vf1.w[1] = *(const u32*)(vp1 + 2);
        vf1.w[2] = 0; vf1.w[3] = 0;
        o0 = o0 * alpha;
        o1 = o1 * alpha;
        o0 = __builtin_amdgcn_mfma_f32_16x16x32_bf16(vf0.v8, pf.v8, o0, 0, 0, 0);
        o1 = __builtin_amdgcn_mfma_f32_16x16x32_bf16(vf1.v8, pf.v8, o1, 0, 0, 0);
      }
    }
    // j-half 1 publishes its partial state
    if (jh == 1){
      mg[tl][0][lane] = o0[0]; mg[tl][1][lane] = o0[1];
      mg[tl][2][lane] = o0[2]; mg[tl][3][lane] = o0[3];
      mg[tl][4][lane] = o1[0]; mg[tl][5][lane] = o1[1];
      mg[tl][6][lane] = o1[2]; mg[tl][7][lane] = o1[3];
      mg[tl][8][lane] = m;     mg[tl][9][lane] = l;
    }
    __syncthreads();
    // j-half 0 merges (exact flash combine) and stores
    if (jh == 0 && active && q0 + lr < len){
      float m2 = mg[tl][8][lane], l2 = mg[tl][9][lane];
      float mn = fmaxf(m, m2);
      float a  = exp2f(m - mn);
      float a2 = exp2f(m2 - mn);        // empty half: exp2(-3e38-mn) = 0
      float lt = l * a + l2 * a2;       // >= 1 (own max contributes 1)
      float rl = 1.0f / lt;
      float r0 = (o0[0]*a + mg[tl][0][lane]*a2) * rl;
      float r1 = (o0[1]*a + mg[tl][1][lane]*a2) * rl;
      float r2 = (o0[2]*a + mg[tl][2][lane]*a2) * rl;
      float r3 = (o0[3]*a + mg[tl][3][lane]*a2) * rl;
      float r4 = (o1[0]*a + mg[tl][4][lane]*a2) * rl;
      float r5 = (o1[1]*a + mg[tl][5][lane]*a2) * rl;
      float r6 = (o1[2]*a + mg[tl][6][lane]*a2) * rl;
      float r7 = (o1[3]*a + mg[tl][7][lane]*a2) * rl;
      u16* orow = out + (size_t)(start + q0 + lr) * HID + hd * HD;
      int dbase = lq * 4;
      *(u32*)&orow[dbase]          = (u32)f2bf(r0) | ((u32)f2bf(r1) << 16);
      *(u32*)&orow[dbase + 2]      = (u32)f2bf(r2) | ((u32)f2bf(r3) << 16);
      *(u32*)&orow[16 + dbase]     = (u32)f2bf(r4) | ((u32)f2bf(r5) << 16);
      *(u32*)&orow[16 + dbase + 2] = (u32)f2bf(r6) | ((u32)f2bf(r7) << 16);
    }
    __syncthreads();
  }
}

// ---------------------------------------------------------------------------
// proj: C = ao * Wo + bo + x (f32 out). Baseline gemm structure; B-frag built
// from Wo f32 directly (same f2bf -> values identical to the old Wt path).
__global__ __launch_bounds__(256) void proj_kernel(const u16* __restrict__ ao,
    const float* __restrict__ Wo, const float* __restrict__ bo,
    const float* __restrict__ x, float* __restrict__ out){
  int gw = blockIdx.x * 4 + (threadIdx.x >> 6);
  int lane = threadIdx.x & 63;
  int lr = lane & 15, lq = lane >> 4;
  int m0 = (gw >> 4) * 64;
  int n0 = (gw & 15) * 16;
  f32x4 acc[4] = {};
  const u16* arow = ao + (size_t)(m0 + lr) * HID + lq * 8;
  const float* wbase = Wo + n0 + lr;
  #pragma unroll
  for (int k0 = 0; k0 < HID; k0 += 32){
    union { bf16x8 v; u16 e[8]; } bf;
    const float* wp = wbase + (size_t)(k0 + lq * 8) * HID;
    #pragma unroll
    for (int j = 0; j < 8; j++) bf.e[j] = f2bf(wp[(size_t)j * HID]);
    #pragma unroll
    for (int t = 0; t < 4; t++){
      bf16x8 a = *(const bf16x8*)(arow + (size_t)t * 16 * HID + k0);
      acc[t] = __builtin_amdgcn_mfma_f32_16x16x32_bf16(a, bf.v, acc[t], 0, 0, 0);
    }
  }
  int col = n0 + lr;
  float bb = bo[col];
  #pragma unroll
  for (int t = 0; t < 4; t++){
    #pragma unroll
    for (int r = 0; r < 4; r++){
      size_t row = (size_t)(m0 + 16 * t + lq * 4 + r) * HID + col;
      out[row] = acc[t][r] + bb + x[row];
    }
  }
}

// ---------------------------------------------------------------------------
// ws_size guard: paint an unmistakable sentinel if scratch is insufficient.
__global__ void sentinel_kernel(u32* __restrict__ out, int nwords){
  int i = blockIdx.x * 256 + threadIdx.x;
  if (i < nwords) out[i] = 0x46404640u;
}

// ---------------------------------------------------------------------------
extern "C" void kernel_launch(void* const* d_in, const int* in_sizes, int n_in,
                              void* d_out, int out_size, void* d_ws, size_t ws_size,
                              hipStream_t stream){
  const float* x   = (const float*)d_in[0];
  const int* batch = (const int*)d_in[1];
  const float* Wq = (const float*)d_in[2],  *bq = (const float*)d_in[3];
  const float* Wk = (const float*)d_in[4],  *bk = (const float*)d_in[5];
  const float* Wv = (const float*)d_in[6],  *bv = (const float*)d_in[7];
  const float* Wo = (const float*)d_in[8],  *bo = (const float*)d_in[9];
  const float* gamma = (const float*)d_in[10], *beta = (const float*)d_in[11];

  const size_t BUF  = (size_t)NNODES * HID * 2;   // 2 MB each (bf16)
  const size_t NEED = 1024 + 4 * BUF;             // ~8.4 MB

  if (ws_size < NEED){
    int nwords = out_size / 2;
    sentinel_kernel<<<(nwords + 255) / 256, 256, 0, stream>>>((u32*)d_out, nwords);
    return;
  }

  // batch dtype from the harness-reported byte size: int64 -> stride 2.
  int bstride = (in_sizes[1] >= NNODES * 8) ? 2 : 1;

  char* w = (char*)d_ws;
  u16* qb = (u16*)(w + 1024);
  u16* kb = qb + (size_t)NNODES * HID;
  u16* vb = kb + (size_t)NNODES * HID;
  u16* ao = vb + (size_t)NNODES * HID;

  lnqkv_kernel<<<dim3(256, 3), 256, 0, stream>>>(x, gamma, beta, Wq, Wk, Wv,
                                                 bq, bk, bv, qb, kb, vb);
  attn_kernel<<<dim3(4, NG * NH), 512, 0, stream>>>(qb, kb, vb, batch, bstride, ao);
  proj_kernel<<<256, 256, 0, stream>>>(ao, Wo, bo, x, (float*)d_out);
}

// Round 9
// 115.709 us; speedup vs baseline: 4.0286x; 1.0007x over previous
//
#include <hip/hip_runtime.h>

#define NNODES 4096
#define HID 256
#define NG 16
#define NH 8
#define HD 32
#define LN_EPS 1e-5f
// (1/sqrt(32)) * log2(e): softmax in exp2 domain (exact wrt softmax)
#define QSCALE (0.17677669529663687f * 1.4426950408889634f)
#define HLS 264           // LDS h-tile row stride (elems)

typedef unsigned short u16;
typedef unsigned int u32;
typedef __bf16 bf16x8 __attribute__((ext_vector_type(8)));
typedef float f32x4 __attribute__((ext_vector_type(4)));

__device__ __forceinline__ u16 f2bf(float f){
  union { float f; u32 i; } c; c.f = f;
  u32 x = c.i;
  return (u16)((x + 0x7fffu + ((x >> 16) & 1u)) >> 16);  // RNE
}

// ---------------------------------------------------------------------------
// lnqkv: fused LayerNorm + QKV GEMM (r6-passed, verbatim). Grid (256, 3) x 256.
__global__ __launch_bounds__(256) void lnqkv_kernel(
    const float* __restrict__ x, const float* __restrict__ gamma,
    const float* __restrict__ beta,
    const float* __restrict__ Wq, const float* __restrict__ Wk,
    const float* __restrict__ Wv,
    const float* __restrict__ bq, const float* __restrict__ bk,
    const float* __restrict__ bv,
    u16* __restrict__ qb, u16* __restrict__ kb, u16* __restrict__ vb){
  __shared__ u16 hl[64][HLS];
  int bid = blockIdx.x;            // 0..255
  int which = blockIdx.y;          // 0 = Q, 1 = K, 2 = V
  int wave = threadIdx.x >> 6, lane = threadIdx.x & 63;
  int m0 = (bid >> 2) * 64;                  // 64-row tile
  int nb = (bid & 3) * 64 + wave * 16;       // wave's 16-col slice
  const float* W    = (which == 0) ? Wq : (which == 1) ? Wk : Wv;
  const float* bias = (which == 0) ? bq : (which == 1) ? bk : bv;
  u16* out          = (which == 0) ? qb : (which == 1) ? kb : vb;

  // ---- LN: wave handles rows wave*16..+15, 4 rows at a time.
  int rsub = lane >> 4;
  int c16  = lane & 15;
  float4 g0 = *(const float4*)(gamma + c16 * 16 + 0);
  float4 g1 = *(const float4*)(gamma + c16 * 16 + 4);
  float4 g2 = *(const float4*)(gamma + c16 * 16 + 8);
  float4 g3 = *(const float4*)(gamma + c16 * 16 + 12);
  float4 t0 = *(const float4*)(beta + c16 * 16 + 0);
  float4 t1 = *(const float4*)(beta + c16 * 16 + 4);
  float4 t2 = *(const float4*)(beta + c16 * 16 + 8);
  float4 t3 = *(const float4*)(beta + c16 * 16 + 12);
  float ga[16] = {g0.x,g0.y,g0.z,g0.w, g1.x,g1.y,g1.z,g1.w,
                  g2.x,g2.y,g2.z,g2.w, g3.x,g3.y,g3.z,g3.w};
  float bt[16] = {t0.x,t0.y,t0.z,t0.w, t1.x,t1.y,t1.z,t1.w,
                  t2.x,t2.y,t2.z,t2.w, t3.x,t3.y,t3.z,t3.w};
  #pragma unroll
  for (int b = 0; b < 4; b++){
    int rloc = wave * 16 + b * 4 + rsub;
    const float* xr = x + (size_t)(m0 + rloc) * HID + c16 * 16;
    float4 v0 = *(const float4*)(xr + 0);
    float4 v1 = *(const float4*)(xr + 4);
    float4 v2 = *(const float4*)(xr + 8);
    float4 v3 = *(const float4*)(xr + 12);
    float e[16] = {v0.x,v0.y,v0.z,v0.w, v1.x,v1.y,v1.z,v1.w,
                   v2.x,v2.y,v2.z,v2.w, v3.x,v3.y,v3.z,v3.w};
    float s = 0.f;
    #pragma unroll
    for (int i = 0; i < 16; i++) s += e[i];
    s += __shfl_xor(s, 1); s += __shfl_xor(s, 2);
    s += __shfl_xor(s, 4); s += __shfl_xor(s, 8);
    float mu = s * (1.0f / HID);
    float vv = 0.f;
    #pragma unroll
    for (int i = 0; i < 16; i++){ e[i] -= mu; vv += e[i] * e[i]; }
    vv += __shfl_xor(vv, 1); vv += __shfl_xor(vv, 2);
    vv += __shfl_xor(vv, 4); vv += __shfl_xor(vv, 8);
    float rs = rsqrtf(vv * (1.0f / HID) + LN_EPS);
    u32 pk[8];
    #pragma unroll
    for (int i = 0; i < 8; i++){
      float o0 = e[2*i]     * rs * ga[2*i]     + bt[2*i];
      float o1 = e[2*i + 1] * rs * ga[2*i + 1] + bt[2*i + 1];
      pk[i] = (u32)f2bf(o0) | ((u32)f2bf(o1) << 16);
    }
    *(uint4*)&hl[rloc][c16 * 16]     = make_uint4(pk[0], pk[1], pk[2], pk[3]);
    *(uint4*)&hl[rloc][c16 * 16 + 8] = make_uint4(pk[4], pk[5], pk[6], pk[7]);
  }
  __syncthreads();

  // ---- GEMM: wave = 64m x 16n; A from LDS h-tile, B from f32 W (strided).
  int lr = lane & 15, lq = lane >> 4;
  f32x4 acc[4] = {};
  const float* wbase = W + nb + lr;
  #pragma unroll
  for (int k0 = 0; k0 < HID; k0 += 32){
    union { bf16x8 v; u16 e[8]; } bf;
    const float* wp = wbase + (size_t)(k0 + lq * 8) * HID;
    #pragma unroll
    for (int j = 0; j < 8; j++) bf.e[j] = f2bf(wp[(size_t)j * HID]);
    #pragma unroll
    for (int t = 0; t < 4; t++){
      bf16x8 a = *(const bf16x8*)&hl[t * 16 + lr][k0 + lq * 8];
      acc[t] = __builtin_amdgcn_mfma_f32_16x16x32_bf16(a, bf.v, acc[t], 0, 0, 0);
    }
  }
  int col = nb + lr;
  float bb = bias[col];
  #pragma unroll
  for (int t = 0; t < 4; t++){
    #pragma unroll
    for (int r = 0; r < 4; r++){
      int row = m0 + 16 * t + lq * 4 + r;
      out[(size_t)row * HID + col] = f2bf(acc[t][r] + bb);
    }
  }
}

// ---------------------------------------------------------------------------
// MFMA flash attention, register-only variant. Identical to the r6-passed
// kernel (per-graph blocks, len masks, ballot lower_bound, wave-pair j-split
// with exact LDS merge) EXCEPT both K and V come straight from global:
// K as a 16B A-frag load (identical addressing to r6's staged values), V as
// 8 independent strided u16 loads per tile (the exact fragment elements --
// V^T[d = lr / 16+lr][j = lq*4+i]). No in-wave LDS transpose (r7/r8's
// suspected race), no staging loops, no staging barrier. Masking equivalence
// with r6: every tile has j0 < len, so invalid j get p = 0 exactly; beyond-len
// K/V rows are finite lnqkv outputs contributing st*0 / V*0.
__global__ __launch_bounds__(512, 4) void attn_kernel(const u16* __restrict__ q,
    const u16* __restrict__ k, const u16* __restrict__ v,
    const int* __restrict__ batch, int bstride, u16* __restrict__ out){
  __shared__ float mg[4][10][64];       // merge: [tile][o0x4,o1x4,m,l][lane]
  __shared__ int s_se[2];
  int gh = blockIdx.y;
  int g = gh >> 3, hd = gh & 7;
  int wave = threadIdx.x >> 6, lane = threadIdx.x & 63;
  // ---- lower_bound(batch, g) / (g+1): waves 0 and 1, two ballot rounds.
  if (wave < 2){
    int target = g + wave;
    int p = batch[(size_t)(lane * 64) * bstride];
    int c = __popcll(__ballot(p < target));
    int lo = 0;
    if (c > 0){
      int base = (c - 1) * 64 + 1;
      int idx = base + lane;
      int val = (idx < NNODES) ? batch[(size_t)idx * bstride] : 0x7fffffff;
      lo = base + __popcll(__ballot(val < target));
    }
    if (lane == 0) s_se[wave] = lo;
  }
  __syncthreads();
  int start = s_se[0], end = s_se[1];
  int len = end - start;
  if (len <= 0) return;               // block-uniform
  int ntj = (len + 15) >> 4;          // 16-row j-tiles (also q-tiles)
  int lq = lane >> 4, lr = lane & 15;
  int tl = wave & 3;                  // tile slot within block
  int jh = wave >> 2;                 // j-half (0 or 1)
  int nouter = (ntj + 15) >> 4;       // usually 1-2
  for (int it = 0; it < nouter; it++){
    int tq = it * 16 + blockIdx.x * 4 + tl;
    bool active = tq < ntj;
    int q0 = tq << 4;
    float m = -3.0e38f, l = 0.f;
    f32x4 o0 = {0.f,0.f,0.f,0.f}, o1 = {0.f,0.f,0.f,0.f};
    if (active){
      // Q B-frag, register-resident. Rows past len read adjacent ws memory
      // (finite bf16), masked at the store.
      bf16x8 qf = *(const bf16x8*)&q[(size_t)(start + q0 + lr) * HID + hd * HD + lq * 8];
      int half = (ntj + 1) >> 1;
      int jt0 = jh ? half : 0;
      int jt1 = jh ? ntj : half;
      for (int jt = jt0; jt < jt1; jt++){
        int j0 = jt << 4;
        // K A-frag direct from global (clamped row; rows >= len masked below)
        int krow = start + j0 + lr;
        if (krow > NNODES - 1) krow = NNODES - 1;
        bf16x8 kf = *(const bf16x8*)&k[(size_t)krow * HID + hd * HD + lq * 8];
        // V fragment elements: 8 independent strided u16 loads, issued early
        // so their latency hides under the QK MFMA + softmax VALU chain.
        u16 va[4], vc[4];
        #pragma unroll
        for (int i = 0; i < 4; i++){
          int vrow = start + j0 + lq * 4 + i;
          if (vrow > NNODES - 1) vrow = NNODES - 1;
          const u16* vp = &v[(size_t)vrow * HID + hd * HD + lr];
          va[i] = vp[0];
          vc[i] = vp[16];
        }
        f32x4 st = __builtin_amdgcn_mfma_f32_16x16x32_bf16(kf, qf,
                     (f32x4){0.f,0.f,0.f,0.f}, 0, 0, 0);
        int jb = j0 + lq * 4;
        float s0 = (jb + 0 < len) ? st[0] * QSCALE : -3.0e38f;
        float s1 = (jb + 1 < len) ? st[1] * QSCALE : -3.0e38f;
        float s2 = (jb + 2 < len) ? st[2] * QSCALE : -3.0e38f;
        float s3 = (jb + 3 < len) ? st[3] * QSCALE : -3.0e38f;
        float tm = fmaxf(fmaxf(s0, s1), fmaxf(s2, s3));
        tm = fmaxf(tm, __shfl_xor(tm, 16));
        tm = fmaxf(tm, __shfl_xor(tm, 32));
        float mn = fmaxf(m, tm);
        float alpha = exp2f(m - mn);       // first tile: exp2(-huge) = 0
        float p0 = exp2f(s0 - mn), p1 = exp2f(s1 - mn);
        float p2 = exp2f(s2 - mn), p3 = exp2f(s3 - mn);
        float ps = (p0 + p1) + (p2 + p3);
        ps += __shfl_xor(ps, 16);
        ps += __shfl_xor(ps, 32);
        l = l * alpha + ps;
        m = mn;
        union { bf16x8 v8; u32 w[4]; } pf, vf0, vf1;
        pf.w[0] = (u32)f2bf(p0) | ((u32)f2bf(p1) << 16);
        pf.w[1] = (u32)f2bf(p2) | ((u32)f2bf(p3) << 16);
        pf.w[2] = 0; pf.w[3] = 0;
        vf0.w[0] = (u32)va[0] | ((u32)va[1] << 16);
        vf0.w[1] = (u32)va[2] | ((u32)va[3] << 16);
        vf0.w[2] = 0; vf0.w[3] = 0;
        vf1.w[0] = (u32)vc[0] | ((u32)vc[1] << 16);
        vf1.w[1] = (u32)vc[2] | ((u32)vc[3] << 16);
        vf1.w[2] = 0; vf1.w[3] = 0;
        o0 = o0 * alpha;
        o1 = o1 * alpha;
        o0 = __builtin_amdgcn_mfma_f32_16x16x32_bf16(vf0.v8, pf.v8, o0, 0, 0, 0);
        o1 = __builtin_amdgcn_mfma_f32_16x16x32_bf16(vf1.v8, pf.v8, o1, 0, 0, 0);
      }
    }
    // j-half 1 publishes its partial state
    if (jh == 1){
      mg[tl][0][lane] = o0[0]; mg[tl][1][lane] = o0[1];
      mg[tl][2][lane] = o0[2]; mg[tl][3][lane] = o0[3];
      mg[tl][4][lane] = o1[0]; mg[tl][5][lane] = o1[1];
      mg[tl][6][lane] = o1[2]; mg[tl][7][lane] = o1[3];
      mg[tl][8][lane] = m;     mg[tl][9][lane] = l;
    }
    __syncthreads();
    // j-half 0 merges (exact flash combine) and stores
    if (jh == 0 && active && q0 + lr < len){
      float m2 = mg[tl][8][lane], l2 = mg[tl][9][lane];
      float mn = fmaxf(m, m2);
      float a  = exp2f(m - mn);
      float a2 = exp2f(m2 - mn);        // empty half: exp2(-3e38-mn) = 0
      float lt = l * a + l2 * a2;       // >= 1 (own max contributes 1)
      float rl = 1.0f / lt;
      float r0 = (o0[0]*a + mg[tl][0][lane]*a2) * rl;
      float r1 = (o0[1]*a + mg[tl][1][lane]*a2) * rl;
      float r2 = (o0[2]*a + mg[tl][2][lane]*a2) * rl;
      float r3 = (o0[3]*a + mg[tl][3][lane]*a2) * rl;
      float r4 = (o1[0]*a + mg[tl][4][lane]*a2) * rl;
      float r5 = (o1[1]*a + mg[tl][5][lane]*a2) * rl;
      float r6 = (o1[2]*a + mg[tl][6][lane]*a2) * rl;
      float r7 = (o1[3]*a + mg[tl][7][lane]*a2) * rl;
      u16* orow = out + (size_t)(start + q0 + lr) * HID + hd * HD;
      int dbase = lq * 4;
      *(u32*)&orow[dbase]          = (u32)f2bf(r0) | ((u32)f2bf(r1) << 16);
      *(u32*)&orow[dbase + 2]      = (u32)f2bf(r2) | ((u32)f2bf(r3) << 16);
      *(u32*)&orow[16 + dbase]     = (u32)f2bf(r4) | ((u32)f2bf(r5) << 16);
      *(u32*)&orow[16 + dbase + 2] = (u32)f2bf(r6) | ((u32)f2bf(r7) << 16);
    }
    __syncthreads();
  }
}

// ---------------------------------------------------------------------------
// proj: C = ao * Wo + bo + x (f32 out). r6-passed, verbatim.
__global__ __launch_bounds__(256) void proj_kernel(const u16* __restrict__ ao,
    const float* __restrict__ Wo, const float* __restrict__ bo,
    const float* __restrict__ x, float* __restrict__ out){
  int gw = blockIdx.x * 4 + (threadIdx.x >> 6);
  int lane = threadIdx.x & 63;
  int lr = lane & 15, lq = lane >> 4;
  int m0 = (gw >> 4) * 64;
  int n0 = (gw & 15) * 16;
  f32x4 acc[4] = {};
  const u16* arow = ao + (size_t)(m0 + lr) * HID + lq * 8;
  const float* wbase = Wo + n0 + lr;
  #pragma unroll
  for (int k0 = 0; k0 < HID; k0 += 32){
    union { bf16x8 v; u16 e[8]; } bf;
    const float* wp = wbase + (size_t)(k0 + lq * 8) * HID;
    #pragma unroll
    for (int j = 0; j < 8; j++) bf.e[j] = f2bf(wp[(size_t)j * HID]);
    #pragma unroll
    for (int t = 0; t < 4; t++){
      bf16x8 a = *(const bf16x8*)(arow + (size_t)t * 16 * HID + k0);
      acc[t] = __builtin_amdgcn_mfma_f32_16x16x32_bf16(a, bf.v, acc[t], 0, 0, 0);
    }
  }
  int col = n0 + lr;
  float bb = bo[col];
  #pragma unroll
  for (int t = 0; t < 4; t++){
    #pragma unroll
    for (int r = 0; r < 4; r++){
      size_t row = (size_t)(m0 + 16 * t + lq * 4 + r) * HID + col;
      out[row] = acc[t][r] + bb + x[row];
    }
  }
}

// ---------------------------------------------------------------------------
// ws_size guard: paint an unmistakable sentinel if scratch is insufficient.
__global__ void sentinel_kernel(u32* __restrict__ out, int nwords){
  int i = blockIdx.x * 256 + threadIdx.x;
  if (i < nwords) out[i] = 0x46404640u;
}

// ---------------------------------------------------------------------------
extern "C" void kernel_launch(void* const* d_in, const int* in_sizes, int n_in,
                              void* d_out, int out_size, void* d_ws, size_t ws_size,
                              hipStream_t stream){
  const float* x   = (const float*)d_in[0];
  const int* batch = (const int*)d_in[1];
  const float* Wq = (const float*)d_in[2],  *bq = (const float*)d_in[3];
  const float* Wk = (const float*)d_in[4],  *bk = (const float*)d_in[5];
  const float* Wv = (const float*)d_in[6],  *bv = (const float*)d_in[7];
  const float* Wo = (const float*)d_in[8],  *bo = (const float*)d_in[9];
  const float* gamma = (const float*)d_in[10], *beta = (const float*)d_in[11];

  const size_t BUF  = (size_t)NNODES * HID * 2;   // 2 MB each (bf16)
  const size_t NEED = 1024 + 4 * BUF;             // ~8.4 MB

  if (ws_size < NEED){
    int nwords = out_size / 2;
    sentinel_kernel<<<(nwords + 255) / 256, 256, 0, stream>>>((u32*)d_out, nwords);
    return;
  }

  // batch dtype from the harness-reported byte size: int64 -> stride 2.
  int bstride = (in_sizes[1] >= NNODES * 8) ? 2 : 1;

  char* w = (char*)d_ws;
  u16* qb = (u16*)(w + 1024);
  u16* kb = qb + (size_t)NNODES * HID;
  u16* vb = kb + (size_t)NNODES * HID;
  u16* ao = vb + (size_t)NNODES * HID;

  lnqkv_kernel<<<dim3(256, 3), 256, 0, stream>>>(x, gamma, beta, Wq, Wk, Wv,
                                                 bq, bk, bv, qb, kb, vb);
  attn_kernel<<<dim3(4, NG * NH), 512, 0, stream>>>(qb, kb, vb, batch, bstride, ao);
  proj_kernel<<<256, 256, 0, stream>>>(ao, Wo, bo, x, (float*)d_out);
}

// Round 10
// 114.789 us; speedup vs baseline: 4.0609x; 1.0080x over previous
//
#include <hip/hip_runtime.h>

#define NNODES 4096
#define HID 256
#define NG 16
#define NH 8
#define HD 32
#define LN_EPS 1e-5f
// (1/sqrt(32)) * log2(e): softmax in exp2 domain (exact wrt softmax)
#define QSCALE (0.17677669529663687f * 1.4426950408889634f)
#define HLS 264           // LDS h-tile row stride (elems)
#define AOS 264           // LDS ao-tile row stride (elems)

typedef unsigned short u16;
typedef unsigned int u32;
typedef __bf16 bf16x8 __attribute__((ext_vector_type(8)));
typedef float f32x4 __attribute__((ext_vector_type(4)));

__device__ __forceinline__ u16 f2bf(float f){
  union { float f; u32 i; } c; c.f = f;
  u32 x = c.i;
  return (u16)((x + 0x7fffu + ((x >> 16) & 1u)) >> 16);  // RNE
}

// ---------------------------------------------------------------------------
// lnqkv: fused LayerNorm + QKV GEMM (y = 0..2; r6/r9-passed verbatim) +
// Wo transpose (y = 3, bid < 64; byte-identical to the r0-r4-proven prep
// transpose: WoT[n][k] = f2bf(Wo[k][n])).
__global__ __launch_bounds__(256) void lnqkv_kernel(
    const float* __restrict__ x, const float* __restrict__ gamma,
    const float* __restrict__ beta,
    const float* __restrict__ Wq, const float* __restrict__ Wk,
    const float* __restrict__ Wv, const float* __restrict__ Wo,
    const float* __restrict__ bq, const float* __restrict__ bk,
    const float* __restrict__ bv,
    u16* __restrict__ qb, u16* __restrict__ kb, u16* __restrict__ vb,
    u16* __restrict__ WoT){
  __shared__ u16 hl[64][HLS];
  int bid = blockIdx.x;            // 0..255
  int which = blockIdx.y;          // 0 = Q, 1 = K, 2 = V, 3 = Wo transpose
  if (which == 3){
    if (bid >= 64) return;
    u16 (*tl)[33] = (u16(*)[33])hl;
    int bx = (bid & 7) * 32, by = (bid >> 3) * 32;
    int tx = threadIdx.x & 31, ty = threadIdx.x >> 5;   // 32 x 8
    #pragma unroll
    for (int r = 0; r < 32; r += 8)
      tl[ty + r][tx] = f2bf(Wo[(size_t)(by + ty + r) * HID + bx + tx]);
    __syncthreads();
    #pragma unroll
    for (int r = 0; r < 32; r += 8)
      WoT[(size_t)(bx + ty + r) * HID + by + tx] = tl[tx][ty + r];
    return;
  }
  int wave = threadIdx.x >> 6, lane = threadIdx.x & 63;
  int m0 = (bid >> 2) * 64;                  // 64-row tile
  int nb = (bid & 3) * 64 + wave * 16;       // wave's 16-col slice
  const float* W    = (which == 0) ? Wq : (which == 1) ? Wk : Wv;
  const float* bias = (which == 0) ? bq : (which == 1) ? bk : bv;
  u16* out          = (which == 0) ? qb : (which == 1) ? kb : vb;

  // ---- LN: wave handles rows wave*16..+15, 4 rows at a time.
  int rsub = lane >> 4;
  int c16  = lane & 15;
  float4 g0 = *(const float4*)(gamma + c16 * 16 + 0);
  float4 g1 = *(const float4*)(gamma + c16 * 16 + 4);
  float4 g2 = *(const float4*)(gamma + c16 * 16 + 8);
  float4 g3 = *(const float4*)(gamma + c16 * 16 + 12);
  float4 t0 = *(const float4*)(beta + c16 * 16 + 0);
  float4 t1 = *(const float4*)(beta + c16 * 16 + 4);
  float4 t2 = *(const float4*)(beta + c16 * 16 + 8);
  float4 t3 = *(const float4*)(beta + c16 * 16 + 12);
  float ga[16] = {g0.x,g0.y,g0.z,g0.w, g1.x,g1.y,g1.z,g1.w,
                  g2.x,g2.y,g2.z,g2.w, g3.x,g3.y,g3.z,g3.w};
  float bt[16] = {t0.x,t0.y,t0.z,t0.w, t1.x,t1.y,t1.z,t1.w,
                  t2.x,t2.y,t2.z,t2.w, t3.x,t3.y,t3.z,t3.w};
  #pragma unroll
  for (int b = 0; b < 4; b++){
    int rloc = wave * 16 + b * 4 + rsub;
    const float* xr = x + (size_t)(m0 + rloc) * HID + c16 * 16;
    float4 v0 = *(const float4*)(xr + 0);
    float4 v1 = *(const float4*)(xr + 4);
    float4 v2 = *(const float4*)(xr + 8);
    float4 v3 = *(const float4*)(xr + 12);
    float e[16] = {v0.x,v0.y,v0.z,v0.w, v1.x,v1.y,v1.z,v1.w,
                   v2.x,v2.y,v2.z,v2.w, v3.x,v3.y,v3.z,v3.w};
    float s = 0.f;
    #pragma unroll
    for (int i = 0; i < 16; i++) s += e[i];
    s += __shfl_xor(s, 1); s += __shfl_xor(s, 2);
    s += __shfl_xor(s, 4); s += __shfl_xor(s, 8);
    float mu = s * (1.0f / HID);
    float vv = 0.f;
    #pragma unroll
    for (int i = 0; i < 16; i++){ e[i] -= mu; vv += e[i] * e[i]; }
    vv += __shfl_xor(vv, 1); vv += __shfl_xor(vv, 2);
    vv += __shfl_xor(vv, 4); vv += __shfl_xor(vv, 8);
    float rs = rsqrtf(vv * (1.0f / HID) + LN_EPS);
    u32 pk[8];
    #pragma unroll
    for (int i = 0; i < 8; i++){
      float o0 = e[2*i]     * rs * ga[2*i]     + bt[2*i];
      float o1 = e[2*i + 1] * rs * ga[2*i + 1] + bt[2*i + 1];
      pk[i] = (u32)f2bf(o0) | ((u32)f2bf(o1) << 16);
    }
    *(uint4*)&hl[rloc][c16 * 16]     = make_uint4(pk[0], pk[1], pk[2], pk[3]);
    *(uint4*)&hl[rloc][c16 * 16 + 8] = make_uint4(pk[4], pk[5], pk[6], pk[7]);
  }
  __syncthreads();

  // ---- GEMM: wave = 64m x 16n; A from LDS h-tile, B from f32 W (strided).
  int lr = lane & 15, lq = lane >> 4;
  f32x4 acc[4] = {};
  const float* wbase = W + nb + lr;
  #pragma unroll
  for (int k0 = 0; k0 < HID; k0 += 32){
    union { bf16x8 v; u16 e[8]; } bf;
    const float* wp = wbase + (size_t)(k0 + lq * 8) * HID;
    #pragma unroll
    for (int j = 0; j < 8; j++) bf.e[j] = f2bf(wp[(size_t)j * HID]);
    #pragma unroll
    for (int t = 0; t < 4; t++){
      bf16x8 a = *(const bf16x8*)&hl[t * 16 + lr][k0 + lq * 8];
      acc[t] = __builtin_amdgcn_mfma_f32_16x16x32_bf16(a, bf.v, acc[t], 0, 0, 0);
    }
  }
  int col = nb + lr;
  float bb = bias[col];
  #pragma unroll
  for (int t = 0; t < 4; t++){
    #pragma unroll
    for (int r = 0; r < 4; r++){
      int row = m0 + 16 * t + lq * 4 + r;
      out[(size_t)row * HID + col] = f2bf(acc[t][r] + bb);
    }
  }
}

// ---------------------------------------------------------------------------
// attnproj: fused flash attention + output projection + residual.
// Grid 256 x 1024 thr (16 waves = 8 heads x 2 j-halves; 4 waves/SIMD).
// Block = one 16-row q-tile. r7 architecture with the CONVICTED in-wave LDS
// V-transpose replaced by r9's PROVEN register-V loads (8 strided u16/tile);
// K direct-global (r9-proven). Per-element graph masks (batch[j]==batch[q],
// clamped reads) allow tiles to straddle graph boundaries. j-halves merge per
// head via the exact flash combine (mg in LDS), normalized ao tile lands in
// LDS bf16, then all 16 waves run the 16m x 256n proj GEMM from ao x WoT
// (B-frag values bit-identical to the f32-strided path), + bias + residual.
__global__ __launch_bounds__(1024, 4) void attnproj_kernel(
    const u16* __restrict__ q, const u16* __restrict__ k,
    const u16* __restrict__ v, const u16* __restrict__ WoT,
    const float* __restrict__ bo, const float* __restrict__ x,
    const int* __restrict__ batch, int bstride, float* __restrict__ out){
  __shared__ u16 ao[16][AOS];           // attention out [q][hid], bf16
  __shared__ float mg[8][10][64];       // merge: [head][o0x4,o1x4,m,l][lane]
  __shared__ int s_se[2];
  int m0 = blockIdx.x * 16;
  int tid = threadIdx.x;
  int wave = tid >> 6, lane = tid & 63;
  int g_lo = batch[(size_t)m0 * bstride];
  int g_hi = batch[(size_t)(m0 + 15) * bstride];
  // ---- j-range via 2-level 64-ary lower_bound (waves 0,1; r6/r9-proven)
  if (wave < 2){
    int target = wave ? (g_hi + 1) : g_lo;
    int p = batch[(size_t)(lane * 64) * bstride];
    int c = __popcll(__ballot(p < target));
    int lo = 0;
    if (c > 0){
      int base = (c - 1) * 64 + 1;
      int idx = base + lane;
      int val = (idx < NNODES) ? batch[(size_t)idx * bstride] : 0x7fffffff;
      lo = base + __popcll(__ballot(val < target));
    }
    if (lane == 0) s_se[wave] = lo;
  }
  __syncthreads();
  int jstart = s_se[0], jend = s_se[1];
  int ntj = (jend - jstart + 15) >> 4;  // >= 1 (covers own 16 rows)
  int lq = lane >> 4, lr = lane & 15;
  int hd = wave & 7;                    // head
  int jh = wave >> 3;                   // j-half

  // ---- attention: wave handles (head hd, j-half jh) for all 16 q-rows
  int qrow = m0 + lr;
  bf16x8 qf = *(const bf16x8*)&q[(size_t)qrow * HID + hd * HD + lq * 8];
  int gq = batch[(size_t)qrow * bstride];
  float m = -3.0e38f, l = 0.f;
  f32x4 o0 = {0.f,0.f,0.f,0.f}, o1 = {0.f,0.f,0.f,0.f};
  {
    int half = (ntj + 1) >> 1;
    int jt0 = jh ? half : 0;
    int jt1 = jh ? ntj : half;
    for (int jt = jt0; jt < jt1; jt++){
      int j0 = jstart + (jt << 4);
      // K A-frag direct from global (clamped row; invalid j masked below)
      int krow = j0 + lr; if (krow > NNODES - 1) krow = NNODES - 1;
      bf16x8 kf = *(const bf16x8*)&k[(size_t)krow * HID + hd * HD + lq * 8];
      // V fragment elements: 8 independent strided u16 loads (r9-proven),
      // issued early so latency hides under QK MFMA + softmax VALU.
      u16 va[4], vc[4];
      #pragma unroll
      for (int i = 0; i < 4; i++){
        int vrow = j0 + lq * 4 + i;
        if (vrow > NNODES - 1) vrow = NNODES - 1;
        const u16* vp = &v[(size_t)vrow * HID + hd * HD + lr];
        va[i] = vp[0];
        vc[i] = vp[16];
      }
      f32x4 st = __builtin_amdgcn_mfma_f32_16x16x32_bf16(kf, qf,
                   (f32x4){0.f,0.f,0.f,0.f}, 0, 0, 0);
      int jb = j0 + lq * 4;
      // per-element graph mask (clamped batch reads)
      int i0 = jb + 0 > 4095 ? 4095 : jb + 0;
      int i1 = jb + 1 > 4095 ? 4095 : jb + 1;
      int i2 = jb + 2 > 4095 ? 4095 : jb + 2;
      int i3 = jb + 3 > 4095 ? 4095 : jb + 3;
      int gj0 = batch[(size_t)i0 * bstride];
      int gj1 = batch[(size_t)i1 * bstride];
      int gj2 = batch[(size_t)i2 * bstride];
      int gj3 = batch[(size_t)i3 * bstride];
      float s0 = (jb + 0 < jend && gj0 == gq) ? st[0] * QSCALE : -3.0e38f;
      float s1 = (jb + 1 < jend && gj1 == gq) ? st[1] * QSCALE : -3.0e38f;
      float s2 = (jb + 2 < jend && gj2 == gq) ? st[2] * QSCALE : -3.0e38f;
      float s3 = (jb + 3 < jend && gj3 == gq) ? st[3] * QSCALE : -3.0e38f;
      float tm = fmaxf(fmaxf(s0, s1), fmaxf(s2, s3));
      tm = fmaxf(tm, __shfl_xor(tm, 16));
      tm = fmaxf(tm, __shfl_xor(tm, 32));
      float mn = fmaxf(m, tm);
      float alpha = exp2f(m - mn);       // first/empty tile: exp2(-huge) = 0
      float p0 = exp2f(s0 - mn), p1 = exp2f(s1 - mn);
      float p2 = exp2f(s2 - mn), p3 = exp2f(s3 - mn);
      float ps = (p0 + p1) + (p2 + p3);
      ps += __shfl_xor(ps, 16);
      ps += __shfl_xor(ps, 32);
      l = l * alpha + ps;
      m = mn;
      union { bf16x8 v8; u32 w[4]; } pf, vf0, vf1;
      pf.w[0] = (u32)f2bf(p0) | ((u32)f2bf(p1) << 16);
      pf.w[1] = (u32)f2bf(p2) | ((u32)f2bf(p3) << 16);
      pf.w[2] = 0; pf.w[3] = 0;
      vf0.w[0] = (u32)va[0] | ((u32)va[1] << 16);
      vf0.w[1] = (u32)va[2] | ((u32)va[3] << 16);
      vf0.w[2] = 0; vf0.w[3] = 0;
      vf1.w[0] = (u32)vc[0] | ((u32)vc[1] << 16);
      vf1.w[1] = (u32)vc[2] | ((u32)vc[3] << 16);
      vf1.w[2] = 0; vf1.w[3] = 0;
      o0 = o0 * alpha;
      o1 = o1 * alpha;
      o0 = __builtin_amdgcn_mfma_f32_16x16x32_bf16(vf0.v8, pf.v8, o0, 0, 0, 0);
      o1 = __builtin_amdgcn_mfma_f32_16x16x32_bf16(vf1.v8, pf.v8, o1, 0, 0, 0);
    }
  }
  // j-half 1 publishes its partial state
  if (jh == 1){
    mg[hd][0][lane] = o0[0]; mg[hd][1][lane] = o0[1];
    mg[hd][2][lane] = o0[2]; mg[hd][3][lane] = o0[3];
    mg[hd][4][lane] = o1[0]; mg[hd][5][lane] = o1[1];
    mg[hd][6][lane] = o1[2]; mg[hd][7][lane] = o1[3];
    mg[hd][8][lane] = m;     mg[hd][9][lane] = l;
  }
  __syncthreads();
  // j-half 0 merges (exact flash combine), normalizes, writes ao tile.
  // Every q-row's diagonal is valid in one half -> that half's l >= 1 at its
  // own max -> lt >= 1 (empty halves contribute exactly 0).
  if (jh == 0){
    float m2 = mg[hd][8][lane], l2 = mg[hd][9][lane];
    float mn = fmaxf(m, m2);
    float a  = exp2f(m - mn);
    float a2 = exp2f(m2 - mn);
    float lt = l * a + l2 * a2;
    float rl = 1.0f / lt;
    float r0 = (o0[0]*a + mg[hd][0][lane]*a2) * rl;
    float r1 = (o0[1]*a + mg[hd][1][lane]*a2) * rl;
    float r2 = (o0[2]*a + mg[hd][2][lane]*a2) * rl;
    float r3 = (o0[3]*a + mg[hd][3][lane]*a2) * rl;
    float r4 = (o1[0]*a + mg[hd][4][lane]*a2) * rl;
    float r5 = (o1[1]*a + mg[hd][5][lane]*a2) * rl;
    float r6 = (o1[2]*a + mg[hd][6][lane]*a2) * rl;
    float r7 = (o1[3]*a + mg[hd][7][lane]*a2) * rl;
    int dbase = hd * HD + lq * 4;
    *(u32*)&ao[lr][dbase]          = (u32)f2bf(r0) | ((u32)f2bf(r1) << 16);
    *(u32*)&ao[lr][dbase + 2]      = (u32)f2bf(r2) | ((u32)f2bf(r3) << 16);
    *(u32*)&ao[lr][dbase + 16]     = (u32)f2bf(r4) | ((u32)f2bf(r5) << 16);
    *(u32*)&ao[lr][dbase + 16 + 2] = (u32)f2bf(r6) | ((u32)f2bf(r7) << 16);
  }
  __syncthreads();

  // ---- proj: 16 waves x 16 cols each; C = ao @ WoT^T + bo + x (f32)
  {
    int n0 = wave * 16;
    f32x4 acc = {};
    const u16* brow = WoT + (size_t)(n0 + lr) * HID + lq * 8;
    #pragma unroll
    for (int k0 = 0; k0 < HID; k0 += 32){
      bf16x8 a = *(const bf16x8*)&ao[lr][k0 + lq * 8];
      bf16x8 b = *(const bf16x8*)(brow + k0);
      acc = __builtin_amdgcn_mfma_f32_16x16x32_bf16(a, b, acc, 0, 0, 0);
    }
    int col = n0 + lr;
    float bb = bo[col];
    #pragma unroll
    for (int r = 0; r < 4; r++){
      size_t idx = (size_t)(m0 + lq * 4 + r) * HID + col;
      out[idx] = acc[r] + bb + x[idx];
    }
  }
}

// ---------------------------------------------------------------------------
// ws_size guard: paint an unmistakable sentinel if scratch is insufficient.
__global__ void sentinel_kernel(u32* __restrict__ out, int nwords){
  int i = blockIdx.x * 256 + threadIdx.x;
  if (i < nwords) out[i] = 0x46404640u;
}

// ---------------------------------------------------------------------------
extern "C" void kernel_launch(void* const* d_in, const int* in_sizes, int n_in,
                              void* d_out, int out_size, void* d_ws, size_t ws_size,
                              hipStream_t stream){
  const float* x   = (const float*)d_in[0];
  const int* batch = (const int*)d_in[1];
  const float* Wq = (const float*)d_in[2],  *bq = (const float*)d_in[3];
  const float* Wk = (const float*)d_in[4],  *bk = (const float*)d_in[5];
  const float* Wv = (const float*)d_in[6],  *bv = (const float*)d_in[7];
  const float* Wo = (const float*)d_in[8],  *bo = (const float*)d_in[9];
  const float* gamma = (const float*)d_in[10], *beta = (const float*)d_in[11];

  const size_t BUF  = (size_t)NNODES * HID * 2;   // 2 MB each (bf16)
  const size_t WOT  = (size_t)HID * HID * 2;      // 128 KB
  const size_t NEED = 1024 + 3 * BUF + WOT;       // ~6.4 MB

  if (ws_size < NEED){
    int nwords = out_size / 2;
    sentinel_kernel<<<(nwords + 255) / 256, 256, 0, stream>>>((u32*)d_out, nwords);
    return;
  }

  // batch dtype from the harness-reported byte size: int64 -> stride 2.
  int bstride = (in_sizes[1] >= NNODES * 8) ? 2 : 1;

  char* w = (char*)d_ws;
  u16* qb  = (u16*)(w + 1024);
  u16* kb  = qb + (size_t)NNODES * HID;
  u16* vb  = kb + (size_t)NNODES * HID;
  u16* WoT = vb + (size_t)NNODES * HID;

  lnqkv_kernel<<<dim3(256, 4), 256, 0, stream>>>(x, gamma, beta, Wq, Wk, Wv, Wo,
                                                 bq, bk, bv, qb, kb, vb, WoT);
  attnproj_kernel<<<256, 1024, 0, stream>>>(qb, kb, vb, WoT, bo, x, batch,
                                            bstride, (float*)d_out);
}

// Round 11
// 113.317 us; speedup vs baseline: 4.1136x; 1.0130x over previous
//
#include <hip/hip_runtime.h>

#define NNODES 4096
#define HID 256
#define NG 16
#define NH 8
#define HD 32
#define LN_EPS 1e-5f
// (1/sqrt(32)) * log2(e): softmax in exp2 domain (exact wrt softmax)
#define QSCALE (0.17677669529663687f * 1.4426950408889634f)
#define HLS 264           // LDS h-tile row stride (elems)
#define AOS 264           // LDS ao-tile row stride (elems)

typedef unsigned short u16;
typedef unsigned int u32;
typedef __bf16 bf16x8 __attribute__((ext_vector_type(8)));
typedef float f32x4 __attribute__((ext_vector_type(4)));

__device__ __forceinline__ u16 f2bf(float f){
  union { float f; u32 i; } c; c.f = f;
  u32 x = c.i;
  return (u16)((x + 0x7fffu + ((x >> 16) & 1u)) >> 16);  // RNE
}

// ---------------------------------------------------------------------------
// lnqkv: fused LayerNorm + QKV GEMM (y = 0..2; r6/r9/r10-passed verbatim) +
// Wo transpose (y = 3, bid < 64; WoT[n][k] = f2bf(Wo[k][n])).
__global__ __launch_bounds__(256) void lnqkv_kernel(
    const float* __restrict__ x, const float* __restrict__ gamma,
    const float* __restrict__ beta,
    const float* __restrict__ Wq, const float* __restrict__ Wk,
    const float* __restrict__ Wv, const float* __restrict__ Wo,
    const float* __restrict__ bq, const float* __restrict__ bk,
    const float* __restrict__ bv,
    u16* __restrict__ qb, u16* __restrict__ kb, u16* __restrict__ vb,
    u16* __restrict__ WoT){
  __shared__ u16 hl[64][HLS];
  int bid = blockIdx.x;            // 0..255
  int which = blockIdx.y;          // 0 = Q, 1 = K, 2 = V, 3 = Wo transpose
  if (which == 3){
    if (bid >= 64) return;
    u16 (*tl)[33] = (u16(*)[33])hl;
    int bx = (bid & 7) * 32, by = (bid >> 3) * 32;
    int tx = threadIdx.x & 31, ty = threadIdx.x >> 5;   // 32 x 8
    #pragma unroll
    for (int r = 0; r < 32; r += 8)
      tl[ty + r][tx] = f2bf(Wo[(size_t)(by + ty + r) * HID + bx + tx]);
    __syncthreads();
    #pragma unroll
    for (int r = 0; r < 32; r += 8)
      WoT[(size_t)(bx + ty + r) * HID + by + tx] = tl[tx][ty + r];
    return;
  }
  int wave = threadIdx.x >> 6, lane = threadIdx.x & 63;
  int m0 = (bid >> 2) * 64;                  // 64-row tile
  int nb = (bid & 3) * 64 + wave * 16;       // wave's 16-col slice
  const float* W    = (which == 0) ? Wq : (which == 1) ? Wk : Wv;
  const float* bias = (which == 0) ? bq : (which == 1) ? bk : bv;
  u16* out          = (which == 0) ? qb : (which == 1) ? kb : vb;

  // ---- LN: wave handles rows wave*16..+15, 4 rows at a time.
  int rsub = lane >> 4;
  int c16  = lane & 15;
  float4 g0 = *(const float4*)(gamma + c16 * 16 + 0);
  float4 g1 = *(const float4*)(gamma + c16 * 16 + 4);
  float4 g2 = *(const float4*)(gamma + c16 * 16 + 8);
  float4 g3 = *(const float4*)(gamma + c16 * 16 + 12);
  float4 t0 = *(const float4*)(beta + c16 * 16 + 0);
  float4 t1 = *(const float4*)(beta + c16 * 16 + 4);
  float4 t2 = *(const float4*)(beta + c16 * 16 + 8);
  float4 t3 = *(const float4*)(beta + c16 * 16 + 12);
  float ga[16] = {g0.x,g0.y,g0.z,g0.w, g1.x,g1.y,g1.z,g1.w,
                  g2.x,g2.y,g2.z,g2.w, g3.x,g3.y,g3.z,g3.w};
  float bt[16] = {t0.x,t0.y,t0.z,t0.w, t1.x,t1.y,t1.z,t1.w,
                  t2.x,t2.y,t2.z,t2.w, t3.x,t3.y,t3.z,t3.w};
  #pragma unroll
  for (int b = 0; b < 4; b++){
    int rloc = wave * 16 + b * 4 + rsub;
    const float* xr = x + (size_t)(m0 + rloc) * HID + c16 * 16;
    float4 v0 = *(const float4*)(xr + 0);
    float4 v1 = *(const float4*)(xr + 4);
    float4 v2 = *(const float4*)(xr + 8);
    float4 v3 = *(const float4*)(xr + 12);
    float e[16] = {v0.x,v0.y,v0.z,v0.w, v1.x,v1.y,v1.z,v1.w,
                   v2.x,v2.y,v2.z,v2.w, v3.x,v3.y,v3.z,v3.w};
    float s = 0.f;
    #pragma unroll
    for (int i = 0; i < 16; i++) s += e[i];
    s += __shfl_xor(s, 1); s += __shfl_xor(s, 2);
    s += __shfl_xor(s, 4); s += __shfl_xor(s, 8);
    float mu = s * (1.0f / HID);
    float vv = 0.f;
    #pragma unroll
    for (int i = 0; i < 16; i++){ e[i] -= mu; vv += e[i] * e[i]; }
    vv += __shfl_xor(vv, 1); vv += __shfl_xor(vv, 2);
    vv += __shfl_xor(vv, 4); vv += __shfl_xor(vv, 8);
    float rs = rsqrtf(vv * (1.0f / HID) + LN_EPS);
    u32 pk[8];
    #pragma unroll
    for (int i = 0; i < 8; i++){
      float o0 = e[2*i]     * rs * ga[2*i]     + bt[2*i];
      float o1 = e[2*i + 1] * rs * ga[2*i + 1] + bt[2*i + 1];
      pk[i] = (u32)f2bf(o0) | ((u32)f2bf(o1) << 16);
    }
    *(uint4*)&hl[rloc][c16 * 16]     = make_uint4(pk[0], pk[1], pk[2], pk[3]);
    *(uint4*)&hl[rloc][c16 * 16 + 8] = make_uint4(pk[4], pk[5], pk[6], pk[7]);
  }
  __syncthreads();

  // ---- GEMM: wave = 64m x 16n; A from LDS h-tile, B from f32 W (strided).
  int lr = lane & 15, lq = lane >> 4;
  f32x4 acc[4] = {};
  const float* wbase = W + nb + lr;
  #pragma unroll
  for (int k0 = 0; k0 < HID; k0 += 32){
    union { bf16x8 v; u16 e[8]; } bf;
    const float* wp = wbase + (size_t)(k0 + lq * 8) * HID;
    #pragma unroll
    for (int j = 0; j < 8; j++) bf.e[j] = f2bf(wp[(size_t)j * HID]);
    #pragma unroll
    for (int t = 0; t < 4; t++){
      bf16x8 a = *(const bf16x8*)&hl[t * 16 + lr][k0 + lq * 8];
      acc[t] = __builtin_amdgcn_mfma_f32_16x16x32_bf16(a, bf.v, acc[t], 0, 0, 0);
    }
  }
  int col = nb + lr;
  float bb = bias[col];
  #pragma unroll
  for (int t = 0; t < 4; t++){
    #pragma unroll
    for (int r = 0; r < 4; r++){
      int row = m0 + 16 * t + lq * 4 + r;
      out[(size_t)row * HID + col] = f2bf(acc[t][r] + bb);
    }
  }
}

// ---------------------------------------------------------------------------
// attnproj: fused flash attention + output projection + residual (r10-passed
// architecture). v2 changes, both latency-motivated:
//  (1) seg-table masks: all 16 waves build seg[0..16] in LDS via the proven
//      ballot lower_bound (one target per wave). Per-row bounds lo_r/hi_r are
//      hoisted out of the j-loop; the per-tile mask is two register compares
//      (equivalent to batch[j]==gq for sorted batch) -- removes 4 dependent
//      global loads per tile from the serial online-softmax chain.
//  (2) one-tile-ahead K/V prefetch into double-buffered registers: tile t+1's
//      K-frag + 8 V elements issue before tile t's softmax, hiding global
//      latency under MFMA+VALU.
// K direct-global + register-V (r9-proven); exact flash merge; ao tile in LDS
// feeds the 16-wave proj GEMM vs WoT, + bias + residual.
__global__ __launch_bounds__(1024, 4) void attnproj_kernel(
    const u16* __restrict__ q, const u16* __restrict__ k,
    const u16* __restrict__ v, const u16* __restrict__ WoT,
    const float* __restrict__ bo, const float* __restrict__ x,
    const int* __restrict__ batch, int bstride, float* __restrict__ out){
  __shared__ u16 ao[16][AOS];           // attention out [q][hid], bf16
  __shared__ float mg[8][10][64];       // merge: [head][o0x4,o1x4,m,l][lane]
  __shared__ int seg[NG + 1];
  int m0 = blockIdx.x * 16;
  int tid = threadIdx.x;
  int wave = tid >> 6, lane = tid & 63;
  // ---- seg table: wave w computes lower_bound(batch, w+1) -> seg[w+1]
  {
    int target = wave + 1;
    int p = batch[(size_t)(lane * 64) * bstride];
    int c = __popcll(__ballot(p < target));
    int lo = 0;
    if (c > 0){
      int base = (c - 1) * 64 + 1;
      int idx = base + lane;
      int val = (idx < NNODES) ? batch[(size_t)idx * bstride] : 0x7fffffff;
      lo = base + __popcll(__ballot(val < target));
    }
    if (lane == 0) seg[target] = lo;
    if (tid == 0) seg[0] = 0;
  }
  __syncthreads();
  int lq = lane >> 4, lr = lane & 15;
  int hd = wave & 7;                    // head
  int jh = wave >> 3;                   // j-half

  // ---- per-row graph bounds (hoisted; mask in-loop is register compares)
  int qrow = m0 + lr;
  int gq = batch[(size_t)qrow * bstride];
  int lo_r = seg[gq], hi_r = seg[gq + 1];
  int g_lo = batch[(size_t)m0 * bstride];
  int g_hi = batch[(size_t)(m0 + 15) * bstride];
  int jstart = seg[g_lo], jend = seg[g_hi + 1];
  int ntj = (jend - jstart + 15) >> 4;  // >= 1 (covers own 16 rows)

  bf16x8 qf = *(const bf16x8*)&q[(size_t)qrow * HID + hd * HD + lq * 8];
  float m = -3.0e38f, l = 0.f;
  f32x4 o0 = {0.f,0.f,0.f,0.f}, o1 = {0.f,0.f,0.f,0.f};
  {
    int half = (ntj + 1) >> 1;
    int jt0 = jh ? half : 0;
    int jt1 = jh ? ntj : half;
    if (jt0 < jt1){
      auto LOADT = [&](int jt, bf16x8& kf, u16* va, u16* vc){
        int j0 = jstart + (jt << 4);
        int krow = j0 + lr; if (krow > NNODES - 1) krow = NNODES - 1;
        kf = *(const bf16x8*)&k[(size_t)krow * HID + hd * HD + lq * 8];
        #pragma unroll
        for (int i = 0; i < 4; i++){
          int vrow = j0 + lq * 4 + i;
          if (vrow > NNODES - 1) vrow = NNODES - 1;
          const u16* vp = &v[(size_t)vrow * HID + hd * HD + lr];
          va[i] = vp[0];
          vc[i] = vp[16];
        }
      };
      bf16x8 kf_c; u16 va_c[4], vc_c[4];
      LOADT(jt0, kf_c, va_c, vc_c);
      for (int jt = jt0; jt < jt1; jt++){
        // prefetch next tile (last iter re-loads current: harmless, branchless)
        bf16x8 kf_n; u16 va_n[4], vc_n[4];
        int jn = (jt + 1 < jt1) ? jt + 1 : jt;
        LOADT(jn, kf_n, va_n, vc_n);
        int j0 = jstart + (jt << 4);
        f32x4 st = __builtin_amdgcn_mfma_f32_16x16x32_bf16(kf_c, qf,
                     (f32x4){0.f,0.f,0.f,0.f}, 0, 0, 0);
        int jb = j0 + lq * 4;
        // register-only graph mask: batch[j]==gq  <=>  lo_r <= j < hi_r
        float s0 = (jb + 0 >= lo_r && jb + 0 < hi_r) ? st[0] * QSCALE : -3.0e38f;
        float s1 = (jb + 1 >= lo_r && jb + 1 < hi_r) ? st[1] * QSCALE : -3.0e38f;
        float s2 = (jb + 2 >= lo_r && jb + 2 < hi_r) ? st[2] * QSCALE : -3.0e38f;
        float s3 = (jb + 3 >= lo_r && jb + 3 < hi_r) ? st[3] * QSCALE : -3.0e38f;
        float tm = fmaxf(fmaxf(s0, s1), fmaxf(s2, s3));
        tm = fmaxf(tm, __shfl_xor(tm, 16));
        tm = fmaxf(tm, __shfl_xor(tm, 32));
        float mn = fmaxf(m, tm);
        float alpha = exp2f(m - mn);       // first/empty tile: exp2(-huge) = 0
        float p0 = exp2f(s0 - mn), p1 = exp2f(s1 - mn);
        float p2 = exp2f(s2 - mn), p3 = exp2f(s3 - mn);
        float ps = (p0 + p1) + (p2 + p3);
        ps += __shfl_xor(ps, 16);
        ps += __shfl_xor(ps, 32);
        l = l * alpha + ps;
        m = mn;
        union { bf16x8 v8; u32 w[4]; } pf, vf0, vf1;
        pf.w[0] = (u32)f2bf(p0) | ((u32)f2bf(p1) << 16);
        pf.w[1] = (u32)f2bf(p2) | ((u32)f2bf(p3) << 16);
        pf.w[2] = 0; pf.w[3] = 0;
        vf0.w[0] = (u32)va_c[0] | ((u32)va_c[1] << 16);
        vf0.w[1] = (u32)va_c[2] | ((u32)va_c[3] << 16);
        vf0.w[2] = 0; vf0.w[3] = 0;
        vf1.w[0] = (u32)vc_c[0] | ((u32)vc_c[1] << 16);
        vf1.w[1] = (u32)vc_c[2] | ((u32)vc_c[3] << 16);
        vf1.w[2] = 0; vf1.w[3] = 0;
        o0 = o0 * alpha;
        o1 = o1 * alpha;
        o0 = __builtin_amdgcn_mfma_f32_16x16x32_bf16(vf0.v8, pf.v8, o0, 0, 0, 0);
        o1 = __builtin_amdgcn_mfma_f32_16x16x32_bf16(vf1.v8, pf.v8, o1, 0, 0, 0);
        kf_c = kf_n;
        #pragma unroll
        for (int i = 0; i < 4; i++){ va_c[i] = va_n[i]; vc_c[i] = vc_n[i]; }
      }
    }
  }
  // j-half 1 publishes its partial state
  if (jh == 1){
    mg[hd][0][lane] = o0[0]; mg[hd][1][lane] = o0[1];
    mg[hd][2][lane] = o0[2]; mg[hd][3][lane] = o0[3];
    mg[hd][4][lane] = o1[0]; mg[hd][5][lane] = o1[1];
    mg[hd][6][lane] = o1[2]; mg[hd][7][lane] = o1[3];
    mg[hd][8][lane] = m;     mg[hd][9][lane] = l;
  }
  __syncthreads();
  // j-half 0 merges (exact flash combine), normalizes, writes ao tile.
  // Every q-row's diagonal is valid in one half -> that half's l >= 1 at its
  // own max -> lt >= 1 (empty halves contribute exactly 0).
  if (jh == 0){
    float m2 = mg[hd][8][lane], l2 = mg[hd][9][lane];
    float mn = fmaxf(m, m2);
    float a  = exp2f(m - mn);
    float a2 = exp2f(m2 - mn);
    float lt = l * a + l2 * a2;
    float rl = 1.0f / lt;
    float r0 = (o0[0]*a + mg[hd][0][lane]*a2) * rl;
    float r1 = (o0[1]*a + mg[hd][1][lane]*a2) * rl;
    float r2 = (o0[2]*a + mg[hd][2][lane]*a2) * rl;
    float r3 = (o0[3]*a + mg[hd][3][lane]*a2) * rl;
    float r4 = (o1[0]*a + mg[hd][4][lane]*a2) * rl;
    float r5 = (o1[1]*a + mg[hd][5][lane]*a2) * rl;
    float r6 = (o1[2]*a + mg[hd][6][lane]*a2) * rl;
    float r7 = (o1[3]*a + mg[hd][7][lane]*a2) * rl;
    int dbase = hd * HD + lq * 4;
    *(u32*)&ao[lr][dbase]          = (u32)f2bf(r0) | ((u32)f2bf(r1) << 16);
    *(u32*)&ao[lr][dbase + 2]      = (u32)f2bf(r2) | ((u32)f2bf(r3) << 16);
    *(u32*)&ao[lr][dbase + 16]     = (u32)f2bf(r4) | ((u32)f2bf(r5) << 16);
    *(u32*)&ao[lr][dbase + 16 + 2] = (u32)f2bf(r6) | ((u32)f2bf(r7) << 16);
  }
  __syncthreads();

  // ---- proj: 16 waves x 16 cols each; C = ao @ WoT^T + bo + x (f32)
  {
    int n0 = wave * 16;
    f32x4 acc = {};
    const u16* brow = WoT + (size_t)(n0 + lr) * HID + lq * 8;
    #pragma unroll
    for (int k0 = 0; k0 < HID; k0 += 32){
      bf16x8 a = *(const bf16x8*)&ao[lr][k0 + lq * 8];
      bf16x8 b = *(const bf16x8*)(brow + k0);
      acc = __builtin_amdgcn_mfma_f32_16x16x32_bf16(a, b, acc, 0, 0, 0);
    }
    int col = n0 + lr;
    float bb = bo[col];
    #pragma unroll
    for (int r = 0; r < 4; r++){
      size_t idx = (size_t)(m0 + lq * 4 + r) * HID + col;
      out[idx] = acc[r] + bb + x[idx];
    }
  }
}

// ---------------------------------------------------------------------------
// ws_size guard: paint an unmistakable sentinel if scratch is insufficient.
__global__ void sentinel_kernel(u32* __restrict__ out, int nwords){
  int i = blockIdx.x * 256 + threadIdx.x;
  if (i < nwords) out[i] = 0x46404640u;
}

// ---------------------------------------------------------------------------
extern "C" void kernel_launch(void* const* d_in, const int* in_sizes, int n_in,
                              void* d_out, int out_size, void* d_ws, size_t ws_size,
                              hipStream_t stream){
  const float* x   = (const float*)d_in[0];
  const int* batch = (const int*)d_in[1];
  const float* Wq = (const float*)d_in[2],  *bq = (const float*)d_in[3];
  const float* Wk = (const float*)d_in[4],  *bk = (const float*)d_in[5];
  const float* Wv = (const float*)d_in[6],  *bv = (const float*)d_in[7];
  const float* Wo = (const float*)d_in[8],  *bo = (const float*)d_in[9];
  const float* gamma = (const float*)d_in[10], *beta = (const float*)d_in[11];

  const size_t BUF  = (size_t)NNODES * HID * 2;   // 2 MB each (bf16)
  const size_t WOT  = (size_t)HID * HID * 2;      // 128 KB
  const size_t NEED = 1024 + 3 * BUF + WOT;       // ~6.4 MB

  if (ws_size < NEED){
    int nwords = out_size / 2;
    sentinel_kernel<<<(nwords + 255) / 256, 256, 0, stream>>>((u32*)d_out, nwords);
    return;
  }

  // batch dtype from the harness-reported byte size: int64 -> stride 2.
  int bstride = (in_sizes[1] >= NNODES * 8) ? 2 : 1;

  char* w = (char*)d_ws;
  u16* qb  = (u16*)(w + 1024);
  u16* kb  = qb + (size_t)NNODES * HID;
  u16* vb  = kb + (size_t)NNODES * HID;
  u16* WoT = vb + (size_t)NNODES * HID;

  lnqkv_kernel<<<dim3(256, 4), 256, 0, stream>>>(x, gamma, beta, Wq, Wk, Wv, Wo,
                                                 bq, bk, bv, qb, kb, vb, WoT);
  attnproj_kernel<<<256, 1024, 0, stream>>>(qb, kb, vb, WoT, bo, x, batch,
                                            bstride, (float*)d_out);
}